// Round 1
// baseline (93.820 us; speedup 1.0000x reference)
//
#include <hip/hip_runtime.h>

#define NN 1000

__device__ __forceinline__ float wave_sum(float v) {
#pragma unroll
    for (int o = 32; o > 0; o >>= 1) v += __shfl_xor(v, o, 64);
    return v;
}

// One block per output row i. 256 threads split the 250 j-quads; two LDS
// block reductions (Xs/S, then Q/R). ~4 blocks/CU resident vs 1 before.
__global__ __launch_bounds__(256) void fused_kernel(
    const float* __restrict__ x,
    const float* __restrict__ W1, const float* __restrict__ b1,
    const float* __restrict__ W2, const float* __restrict__ b2,
    const float* __restrict__ Wf1e, const float* __restrict__ bf1e,
    const float* __restrict__ Wf2e, const float* __restrict__ bf2e,
    const float* __restrict__ Wfk, const float* __restrict__ bfk,
    const float* __restrict__ Wf1v, const float* __restrict__ bf1v,
    const float* __restrict__ Wf2v, const float* __restrict__ bf2v,
    float* __restrict__ out) {
    const int tid  = threadIdx.x;
    const int wave = tid >> 6;
    const int lane = tid & 63;
    const int i    = blockIdx.x;          // one row per block (1000 blocks)
    const bool act = tid < (NN / 4);      // 250 active j-quads

    __shared__ float redA[4][8];          // per-wave Xs partials
    __shared__ float redB[4][18];         // per-wave Q/R partials

    // ---- Issue all global loads up front: this thread's j-quad x 8 batches,
    //      plus the row-i scalars for xsi (uniform -> scalar path). ----
    float4 v[8];
#pragma unroll
    for (int b = 0; b < 8; ++b)
        v[b] = act ? *reinterpret_cast<const float4*>(x + b * NN + 4 * tid)
                   : make_float4(0.f, 0.f, 0.f, 0.f);
    float xsi = 0.f;
#pragma unroll
    for (int b = 0; b < 8; ++b) xsi += x[b * NN + i];

    // ---- Phase-1 reduce: per-batch partial sums -> LDS ----
    float part[8];
#pragma unroll
    for (int b = 0; b < 8; ++b) {
        float s = (v[b].x + v[b].y) + (v[b].z + v[b].w);
        part[b] = wave_sum(s);
    }
    if (lane == 0) {
#pragma unroll
        for (int b = 0; b < 8; ++b) redA[wave][b] = part[b];
    }

    // ---- S-independent constant algebra (overlaps the barrier) ----
    float alpha[2];
#pragma unroll
    for (int f = 0; f < 2; ++f) {
        float a = 0.f;
#pragma unroll
        for (int e = 0; e < 4; ++e) a += W1[e] * Wf1e[(2 * e) * 2 + f];
        alpha[f] = (float)NN * a;
    }
    float gamma[3];
#pragma unroll
    for (int vv = 0; vv < 3; ++vv) {
        float g = 0.f;
#pragma unroll
        for (int f = 0; f < 2; ++f) g += alpha[f] * Wf1v[f * 3 + vv];
        gamma[vv] = g;
    }
    float uA[6], cB[6], vAc[6];
#pragma unroll
    for (int m = 0; m < 2; ++m)
#pragma unroll
        for (int k = 0; k < 3; ++k) {
            float ua = 0.f, ub = 0.f, va = 0.f, vb = 0.f;
#pragma unroll
            for (int e = 0; e < 4; ++e) {
                float wE = Wfk[k * 16 + (2 * e) * 2 + m];
                float wO = Wfk[k * 16 + (2 * e + 1) * 2 + m];
                ua += W2[e] * wE; ub += b2[e] * wE;
                va += W2[e] * wO; vb += b2[e] * wO;
            }
            uA[m * 3 + k]  = ua;
            cB[m * 3 + k]  = ub + vb + bfk[k * 2 + m];
            vAc[m * 3 + k] = va;
        }
    const float LOG2E = 1.4426950408889634f;
    float PA[3], PB[3], pbv[3];
#pragma unroll
    for (int k = 0; k < 3; ++k) {
        float pa = 0.f, pb = 0.f;
#pragma unroll
        for (int vv = 0; vv < 3; ++vv) {
            pa += gamma[vv] * Wf2e[(2 * vv) * 3 + k];
            pb += gamma[vv] * Wf2e[(2 * vv + 1) * 3 + k];
        }
        PA[k] = pa; pbv[k] = pb;
        PB[k] = pb * LOG2E;
    }

    __syncthreads();

    // ---- S-dependent constants ----
    float Xs[8];
#pragma unroll
    for (int b = 0; b < 8; ++b)
        Xs[b] = (redA[0][b] + redA[1][b]) + (redA[2][b] + redA[3][b]);
    const float S = ((Xs[0] + Xs[1]) + (Xs[2] + Xs[3])) +
                    ((Xs[4] + Xs[5]) + (Xs[6] + Xs[7]));
    float Bsum[2];
#pragma unroll
    for (int f = 0; f < 2; ++f) {
        float t0 = 0.f, t1 = 0.f;
#pragma unroll
        for (int e = 0; e < 4; ++e) {
            t0 += b1[e] * Wf1e[(2 * e) * 2 + f];
            t1 += (S * W1[e] + 8.f * (float)NN * b1[e]) * Wf1e[(2 * e + 1) * 2 + f];
        }
        Bsum[f] = 8.f * (float)NN * t0 + t1 + 8.f * (float)NN * bf1e[f];
    }
    float Ds[3];
#pragma unroll
    for (int vv = 0; vv < 3; ++vv) {
        float d = 8.f * bf1v[vv];
#pragma unroll
        for (int f = 0; f < 2; ++f) d += Bsum[f] * Wf1v[f * 3 + vv];
        Ds[vv] = d;
    }
    float AiQ[3];
#pragma unroll
    for (int k = 0; k < 3; ++k) {
        float QA = 0.f, qb = 0.f;
#pragma unroll
        for (int vv = 0; vv < 3; ++vv) {
            QA += Ds[vv] * Wf2e[(2 * vv) * 3 + k];
            qb += Ds[vv] * Wf2e[(2 * vv + 1) * 3 + k];
        }
        AiQ[k] = (PA[k] * xsi + QA + bf2e[k] + qb) * LOG2E;
    }

    // ---- Main loop: 4 softmax entries per thread, register-resident ----
    const float ai0 = AiQ[0], ai1 = AiQ[1], ai2 = AiQ[2];
    const float pb0 = PB[0], pb1 = PB[1], pb2 = PB[2];
    float Q0 = 0.f, Q1 = 0.f;
    float R[8][2];
#pragma unroll
    for (int b = 0; b < 8; ++b) { R[b][0] = 0.f; R[b][1] = 0.f; }

    if (act) {
        const float* vf = reinterpret_cast<const float*>(v);
#pragma unroll
        for (int u = 0; u < 4; ++u) {
            float xs = 0.f;
#pragma unroll
            for (int b = 0; b < 8; ++b) xs += vf[b * 4 + u];
            float l0 = ai0 + pb0 * xs, l1 = ai1 + pb1 * xs, l2 = ai2 + pb2 * xs;
            float mx = fmaxf(l0, fmaxf(l1, l2));
            float e0 = exp2f(l0 - mx), e1 = exp2f(l1 - mx), e2 = exp2f(l2 - mx);
            float inv = 1.f / (e0 + e1 + e2);
            float p0 = e0 * inv, p1 = e1 * inv;
            Q0 += p0; Q1 += p1;
#pragma unroll
            for (int b = 0; b < 8; ++b) {
                float xb = vf[b * 4 + u];
                R[b][0] += p0 * xb;
                R[b][1] += p1 * xb;
            }
        }
    }

    // ---- Phase-2 reduce: 18 values, wave then LDS ----
    Q0 = wave_sum(Q0); Q1 = wave_sum(Q1);
#pragma unroll
    for (int b = 0; b < 8; ++b) {
        R[b][0] = wave_sum(R[b][0]);
        R[b][1] = wave_sum(R[b][1]);
    }
    if (lane == 0) {
        redB[wave][0] = Q0; redB[wave][1] = Q1;
#pragma unroll
        for (int b = 0; b < 8; ++b) {
            redB[wave][2 + 2 * b] = R[b][0];
            redB[wave][3 + 2 * b] = R[b][1];
        }
    }
    __syncthreads();

    // ---- Epilogue: threads 0..7 each write one batch row ----
    if (tid < 8) {
        const int b = tid;
        float q0  = (redB[0][0] + redB[1][0]) + (redB[2][0] + redB[3][0]);
        float q1  = (redB[0][1] + redB[1][1]) + (redB[2][1] + redB[3][1]);
        float Rk0 = (redB[0][2 + 2 * b] + redB[1][2 + 2 * b]) +
                    (redB[2][2 + 2 * b] + redB[3][2 + 2 * b]);
        float Rk1 = (redB[0][3 + 2 * b] + redB[1][3 + 2 * b]) +
                    (redB[2][3 + 2 * b] + redB[3][3 + 2 * b]);
        float xi  = x[b * NN + i];
        float Q2  = (float)NN - q0 - q1;
        float Rk2 = Xs[b] - Rk0 - Rk1;
        float ve[2];
#pragma unroll
        for (int m = 0; m < 2; ++m) {
            ve[m] = q0 * (uA[m * 3 + 0] * xi + cB[m * 3 + 0]) + vAc[m * 3 + 0] * Rk0
                  + q1 * (uA[m * 3 + 1] * xi + cB[m * 3 + 1]) + vAc[m * 3 + 1] * Rk1
                  + Q2 * (uA[m * 3 + 2] * xi + cB[m * 3 + 2]) + vAc[m * 3 + 2] * Rk2;
        }
        out[b * NN + i] = xi + ve[0] * Wf2v[0] + ve[1] * Wf2v[1] + xi * Wf2v[2] + bf2v[0];
    }
}

extern "C" void kernel_launch(void* const* d_in, const int* in_sizes, int n_in,
                              void* d_out, int out_size, void* d_ws, size_t ws_size,
                              hipStream_t stream) {
    const float* x    = (const float*)d_in[0];
    const float* W1   = (const float*)d_in[1];
    const float* b1   = (const float*)d_in[2];
    const float* W2   = (const float*)d_in[3];
    const float* b2   = (const float*)d_in[4];
    const float* Wf1e = (const float*)d_in[5];
    const float* bf1e = (const float*)d_in[6];
    const float* Wf2e = (const float*)d_in[7];
    const float* bf2e = (const float*)d_in[8];
    const float* Wfk  = (const float*)d_in[9];
    const float* bfk  = (const float*)d_in[10];
    const float* Wf1v = (const float*)d_in[11];
    const float* bf1v = (const float*)d_in[12];
    const float* Wf2v = (const float*)d_in[13];
    const float* bf2v = (const float*)d_in[14];

    fused_kernel<<<NN, 256, 0, stream>>>(x, W1, b1, W2, b2, Wf1e, bf1e,
                                         Wf2e, bf2e, Wfk, bfk, Wf1v, bf1v,
                                         Wf2v, bf2v, (float*)d_out);
}